// Round 11
// baseline (78.058 us; speedup 1.0000x reference)
//
#include <hip/hip_runtime.h>
#include <math.h>

// Tropical (max-plus) matmul: out[b,o] = max_k ( x[b,k] + W[o,k] )
// x: (2048,512) f32, W: (512,512) f32, out: (2048,512) f32.
//
// R13 post-mortem: R9 structure reproduces exactly (65.35 vs 65.28us) ->
// model stable: timed = ~42us harness ws-poison fill (fixed) + ~23us
// controllable, cold reads drain-throttled behind the fill's write-back.
// Fused-gate family conclusively worse (98-133us).
// R14: keep the two-kernel shape, drop the W transpose. R11/R12 proved
// (absmax 0.0, twice) the direct column gather of W needs no Wt: per
// candidate, 8 scalar loads @ 2KB stride, ~3 cand/row, W (1MB) L2-hot.
// Removes the 2MB Wt write + ~2MB Wt read from the drain window; prep
// shrinks to a 1MB min/max pass; ws need drops to 512 B.
//
// Exactness: k with x[b,k] < m_b - (Wmax - Wmin) satisfies
// x[b,k] + W[o,k] < m_b + Wmin <= x[b,k*] + W[o,k*] for every o, so the
// max over the surviving candidate superset is bit-identical to the full
// scan; any candidate count is handled (worst case = full scan).

#define B_ROWS 2048
#define K_DIM  512
#define O_DIM  512

// ws layout (floats): [0..127] = 64 (min,max) pairs.
#define WS_NEED_BYTES 512

__global__ __launch_bounds__(256) void prep_minmax(
    const float* __restrict__ W, float* __restrict__ ws)
{
    __shared__ float wmin4[4], wmax4[4];

    const int t  = threadIdx.x;
    const int bx = blockIdx.x;        // 64 blocks, W rows bx*8..+7 (16 KB)
    const float* wbase = W + (size_t)bx * 8 * K_DIM;

    float lmin = INFINITY, lmax = -INFINITY;
#pragma unroll
    for (int q = 0; q < 4; ++q) {
        float4 v = *(const float4*)(wbase + 4 * (t + 256 * q));
        lmin = fminf(lmin, fminf(fminf(v.x, v.y), fminf(v.z, v.w)));
        lmax = fmaxf(lmax, fmaxf(fmaxf(v.x, v.y), fmaxf(v.z, v.w)));
    }
#pragma unroll
    for (int off = 32; off; off >>= 1) {
        lmin = fminf(lmin, __shfl_xor(lmin, off));
        lmax = fmaxf(lmax, __shfl_xor(lmax, off));
    }
    if ((t & 63) == 0) { wmin4[t >> 6] = lmin; wmax4[t >> 6] = lmax; }
    __syncthreads();
    if (t == 0) {
        ws[2 * bx] =
            fminf(fminf(wmin4[0], wmin4[1]), fminf(wmin4[2], wmin4[3]));
        ws[2 * bx + 1] =
            fmaxf(fmaxf(wmax4[0], wmax4[1]), fmaxf(wmax4[2], wmax4[3]));
    }
}

__global__ __launch_bounds__(256) void tropical_sparse(
    const float* __restrict__ x, const float* __restrict__ W,
    const float* __restrict__ ws, float* __restrict__ out)
{
    const int t    = threadIdx.x;
    const int w    = t >> 6;                  // wave 0..3
    const int lane = t & 63;
    const int b    = blockIdx.x * 4 + w;      // row, 512 blocks x 4 = 2048

    // x row: 8 consecutive floats per lane (k = lane*8 .. +7)
    const float* xr = x + (size_t)b * K_DIM + lane * 8;
    float4 xa = *(const float4*)(xr);
    float4 xb = *(const float4*)(xr + 4);
    float xs[8] = {xa.x, xa.y, xa.z, xa.w, xb.x, xb.y, xb.z, xb.w};

    // global W min/max from the 64 per-block pairs (lane l reads pair l)
    float bmin = ws[2 * lane], bmax = ws[2 * lane + 1];
#pragma unroll
    for (int off = 32; off; off >>= 1) {
        bmin = fminf(bmin, __shfl_xor(bmin, off));
        bmax = fmaxf(bmax, __shfl_xor(bmax, off));
    }
    const float dW = bmax - bmin;

    // row max
    float m = xs[0];
#pragma unroll
    for (int i = 1; i < 8; ++i) m = fmaxf(m, xs[i]);
#pragma unroll
    for (int off = 32; off; off >>= 1) m = fmaxf(m, __shfl_xor(m, off));
    const float thr = m - dW;                 // exact pruning bound

    float acc[8];
#pragma unroll
    for (int i = 0; i < 8; ++i) acc[i] = -INFINITY;
    const int o0 = lane * 8;

    // candidates: any k with x[b,k] >= thr (>=1 exists: the argmax itself)
#pragma unroll
    for (int s = 0; s < 8; ++s) {
        unsigned long long mask = __ballot(xs[s] >= thr);
        while (mask) {
            const int src = __ffsll(mask) - 1;
            mask &= mask - 1;
            const float xv = __shfl(xs[s], src);
            const int k = src * 8 + s;
            // direct column gather: W[o0+i][k], 2KB stride, L2-hot (W=1MB)
            const float* wc = W + (size_t)o0 * K_DIM + k;
            float wv[8];
#pragma unroll
            for (int i = 0; i < 8; ++i)
                wv[i] = wc[(size_t)i * K_DIM];
#pragma unroll
            for (int i = 0; i < 8; ++i)
                acc[i] = fmaxf(acc[i], xv + wv[i]);
        }
    }

    float* op = out + (size_t)b * O_DIM + o0;
    *(float4*)(op)     = make_float4(acc[0], acc[1], acc[2], acc[3]);
    *(float4*)(op + 4) = make_float4(acc[4], acc[5], acc[6], acc[7]);
}

// ws-too-small fallback: plain full scan, correct for any input.
__global__ __launch_bounds__(256) void tropical_naive(
    const float* __restrict__ x, const float* __restrict__ W,
    float* __restrict__ out)
{
    const int b = blockIdx.x;
    const int t = threadIdx.x;
#pragma unroll
    for (int half = 0; half < 2; ++half) {
        const int o = t + half * 256;
        const float* wr = W + (size_t)o * K_DIM;
        const float* xr = x + (size_t)b * K_DIM;
        float acc = -INFINITY;
        for (int k = 0; k < K_DIM; ++k)
            acc = fmaxf(acc, xr[k] + wr[k]);
        out[(size_t)b * O_DIM + o] = acc;
    }
}

extern "C" void kernel_launch(void* const* d_in, const int* in_sizes, int n_in,
                              void* d_out, int out_size, void* d_ws, size_t ws_size,
                              hipStream_t stream) {
    const float* x = (const float*)d_in[0];   // (2048, 512)
    const float* W = (const float*)d_in[1];   // (512, 512)
    float* out = (float*)d_out;               // (2048, 512)

    if (ws_size >= WS_NEED_BYTES) {
        prep_minmax<<<64, 256, 0, stream>>>(W, (float*)d_ws);
        tropical_sparse<<<B_ROWS / 4, 256, 0, stream>>>(
            x, W, (const float*)d_ws, out);
    } else {
        tropical_naive<<<B_ROWS, 256, 0, stream>>>(x, W, out);
    }
}

// Round 12
// 64.829 us; speedup vs baseline: 1.2041x; 1.2041x over previous
//
#include <hip/hip_runtime.h>
#include <math.h>

// Tropical (max-plus) matmul: out[b,o] = max_k ( x[b,k] + W[o,k] )
// x: (2048,512) f32, W: (512,512) f32, out: (2048,512) f32.
//
// R14 post-mortem: dropping the W transpose HURT (65.3 -> 78.1us). Column
// gather of row-major W = 64 distinct 64B lines per load instr, 512 lines
// (32KB) per candidate column -> ~200MB request-bound L2 line traffic.
// The Wt layout reads 2KB contiguous per candidate (16x fewer lines); its
// 2MB write + 2MB read round-trip is a cheap stream. Count cachelines,
// not bytes. R11/R12 masked this behind gate-spin overlap.
//
// FINAL (R15 = R9/R13 verbatim, 65.3us reproduced twice): two kernels,
// W-transpose+minmax prep, then exact-pruned sparse gather on Wt.
// Measured search tree: dense full-compute >=88 e2e; fused single-
// dispatch 98-133; no-transpose 78.1; THIS 65.3. Timed floor = ~42us
// harness ws-poison fill (+ write-back drain throttling our cold reads)
// + ~23us controllable, each piece near its drain-degraded service rate.
//
// Exactness: k with x[b,k] < m_b - (Wmax - Wmin) satisfies
// x[b,k] + W[o,k] < m_b + Wmin <= x[b,k*] + W[o,k*] for every o, so the
// max over the surviving candidate superset is bit-identical to the full
// scan; any candidate count is handled (worst case = full scan).

#define B_ROWS 2048
#define K_DIM  512
#define O_DIM  512

// ws layout (floats): [0..127] 64 (min,max) pairs; Wt at float offset 256.
#define WS_WT_OFF 256
#define WS_NEED_BYTES ((size_t)(WS_WT_OFF + K_DIM * O_DIM) * sizeof(float))

__global__ __launch_bounds__(256) void prep_transpose_minmax(
    const float* __restrict__ W, float* __restrict__ ws)
{
    __shared__ float sm[64][65];      // 64x64 tile, padded
    __shared__ float wmin[4], wmax[4];

    const int t  = threadIdx.x;
    const int bx = blockIdx.x;        // 64 blocks: 8x8 tiles of 64x64
    const int tr = (bx >> 3) * 64;    // o-dim (W row) tile base
    const int tc = (bx & 7) * 64;     // k-dim (W col) tile base

    const int lr0 = t >> 4;           // 0..15
    const int lc  = (t & 15) * 4;     // 0..60

    float lmin = INFINITY, lmax = -INFINITY;
#pragma unroll
    for (int q = 0; q < 4; ++q) {
        const int r = lr0 + q * 16;
        float4 v = *(const float4*)(W + (size_t)(tr + r) * K_DIM + tc + lc);
        sm[r][lc + 0] = v.x; sm[r][lc + 1] = v.y;
        sm[r][lc + 2] = v.z; sm[r][lc + 3] = v.w;
        lmin = fminf(lmin, fminf(fminf(v.x, v.y), fminf(v.z, v.w)));
        lmax = fmaxf(lmax, fmaxf(fmaxf(v.x, v.y), fmaxf(v.z, v.w)));
    }
    __syncthreads();

    // transposed write: Wt[k][o]
    float* Wt = ws + WS_WT_OFF;
#pragma unroll
    for (int q = 0; q < 4; ++q) {
        const int kr = lr0 + q * 16;
        float4 v;
        v.x = sm[lc + 0][kr]; v.y = sm[lc + 1][kr];
        v.z = sm[lc + 2][kr]; v.w = sm[lc + 3][kr];
        *(float4*)(Wt + (size_t)(tc + kr) * O_DIM + tr + lc) = v;
    }

    // block min/max -> ws[2*bx], ws[2*bx+1]
#pragma unroll
    for (int off = 32; off; off >>= 1) {
        lmin = fminf(lmin, __shfl_xor(lmin, off));
        lmax = fmaxf(lmax, __shfl_xor(lmax, off));
    }
    if ((t & 63) == 0) { wmin[t >> 6] = lmin; wmax[t >> 6] = lmax; }
    __syncthreads();
    if (t == 0) {
        ws[2 * bx]     = fminf(fminf(wmin[0], wmin[1]), fminf(wmin[2], wmin[3]));
        ws[2 * bx + 1] = fmaxf(fmaxf(wmax[0], wmax[1]), fmaxf(wmax[2], wmax[3]));
    }
}

__global__ __launch_bounds__(256) void tropical_sparse(
    const float* __restrict__ x, const float* __restrict__ ws,
    float* __restrict__ out)
{
    const int t    = threadIdx.x;
    const int w    = t >> 6;                  // wave 0..3
    const int lane = t & 63;
    const int b    = blockIdx.x * 4 + w;      // row, 512 blocks x 4 = 2048
    const float* Wt = ws + WS_WT_OFF;

    // x row: 8 consecutive floats per lane (k = lane*8 .. +7)
    const float* xr = x + (size_t)b * K_DIM + lane * 8;
    float4 xa = *(const float4*)(xr);
    float4 xb = *(const float4*)(xr + 4);
    float xs[8] = {xa.x, xa.y, xa.z, xa.w, xb.x, xb.y, xb.z, xb.w};

    // global W min/max from the 64 per-block pairs (lane l reads pair l)
    float bmin = ws[2 * lane], bmax = ws[2 * lane + 1];
#pragma unroll
    for (int off = 32; off; off >>= 1) {
        bmin = fminf(bmin, __shfl_xor(bmin, off));
        bmax = fmaxf(bmax, __shfl_xor(bmax, off));
    }
    const float dW = bmax - bmin;

    // row max
    float m = xs[0];
#pragma unroll
    for (int i = 1; i < 8; ++i) m = fmaxf(m, xs[i]);
#pragma unroll
    for (int off = 32; off; off >>= 1) m = fmaxf(m, __shfl_xor(m, off));
    const float thr = m - dW;

    float acc[8];
#pragma unroll
    for (int i = 0; i < 8; ++i) acc[i] = -INFINITY;

    const int o0 = lane * 8;
    // candidates: any k with x[b,k] >= thr (>=1 exists: the argmax itself)
#pragma unroll
    for (int s = 0; s < 8; ++s) {
        unsigned long long mask = __ballot(xs[s] >= thr);
        while (mask) {
            const int src = __ffsll(mask) - 1;
            mask &= mask - 1;
            const float xv = __shfl(xs[s], src);
            const int k = src * 8 + s;
            const float* wr = Wt + (size_t)k * O_DIM + o0;   // coalesced, L2-hot
            float4 wa = *(const float4*)(wr);
            float4 wb = *(const float4*)(wr + 4);
            acc[0] = fmaxf(acc[0], xv + wa.x);
            acc[1] = fmaxf(acc[1], xv + wa.y);
            acc[2] = fmaxf(acc[2], xv + wa.z);
            acc[3] = fmaxf(acc[3], xv + wa.w);
            acc[4] = fmaxf(acc[4], xv + wb.x);
            acc[5] = fmaxf(acc[5], xv + wb.y);
            acc[6] = fmaxf(acc[6], xv + wb.z);
            acc[7] = fmaxf(acc[7], xv + wb.w);
        }
    }

    float* op = out + (size_t)b * O_DIM + o0;
    *(float4*)(op)     = make_float4(acc[0], acc[1], acc[2], acc[3]);
    *(float4*)(op + 4) = make_float4(acc[4], acc[5], acc[6], acc[7]);
}

// ws-too-small fallback: plain full scan, correct for any input.
__global__ __launch_bounds__(256) void tropical_naive(
    const float* __restrict__ x, const float* __restrict__ W,
    float* __restrict__ out)
{
    const int b = blockIdx.x;
    const int t = threadIdx.x;
#pragma unroll
    for (int half = 0; half < 2; ++half) {
        const int o = t + half * 256;
        const float* wr = W + (size_t)o * K_DIM;
        const float* xr = x + (size_t)b * K_DIM;
        float acc = -INFINITY;
        for (int k = 0; k < K_DIM; ++k)
            acc = fmaxf(acc, xr[k] + wr[k]);
        out[(size_t)b * O_DIM + o] = acc;
    }
}

extern "C" void kernel_launch(void* const* d_in, const int* in_sizes, int n_in,
                              void* d_out, int out_size, void* d_ws, size_t ws_size,
                              hipStream_t stream) {
    const float* x = (const float*)d_in[0];   // (2048, 512)
    const float* W = (const float*)d_in[1];   // (512, 512)
    float* out = (float*)d_out;               // (2048, 512)

    if (ws_size >= WS_NEED_BYTES) {
        prep_transpose_minmax<<<64, 256, 0, stream>>>(W, (float*)d_ws);
        tropical_sparse<<<B_ROWS / 4, 256, 0, stream>>>(
            x, (const float*)d_ws, out);
    } else {
        tropical_naive<<<B_ROWS, 256, 0, stream>>>(x, W, out);
    }
}